// Round 4
// baseline (244.237 us; speedup 1.0000x reference)
//
#include <hip/hip_runtime.h>
#include <hip/hip_bf16.h>
#include <math.h>

#define T_LEN 20000
#define HID 150
#define STRU 168    // Us / X1s / h1p row stride (shorts)
#define STRPV 176   // Ps / Vs row stride (shorts): 352B rows -> ~2-way banks in phase1

typedef __attribute__((ext_vector_type(8))) __bf16 bf16x8;
typedef __attribute__((ext_vector_type(4))) float f32x4;

__device__ __forceinline__ short f2bf(float f) {
    unsigned u = __float_as_uint(f);
    u = (u + 0x7fff + ((u >> 16) & 1)) >> 16;
    return (short)u;
}

__device__ __forceinline__ unsigned pk2(float a, float b) {
    __hip_bfloat162 h = __float22bfloat162_rn(make_float2(a, b));
    return *(unsigned*)&h;
}

__device__ __forceinline__ bf16x8 cvt8(float4 a, float4 b) {
    union { unsigned u[4]; bf16x8 v; } r;
    r.u[0] = pk2(a.x, a.y);
    r.u[1] = pk2(a.z, a.w);
    r.u[2] = pk2(b.x, b.y);
    r.u[3] = pk2(b.z, b.w);
    return r.v;
}

__device__ __forceinline__ float2 ubf2(unsigned u) {
    return make_float2(__uint_as_float(u << 16),
                       __uint_as_float(u & 0xffff0000u));
}

// ---------------------------------------------------------------------------
// Fragment-order weight regions (shorts), lane = consuming lane (ml|kg<<4):
//   fragA  [0,199680)        30 tiles x 13 ks x 64 x 8   U(0-9) V(10-19) aW1(20-29)
//   fragP  [199680,250880)   10 tiles x 10 ks x 64 x 8   sc_W1 rows 800..1099
//   fragAt2[250880,276480)   10 tiles x  5 ks x 64 x 8   attn_W2
//   fragW2 [276480,302080)   10 tiles x  5 ks x 64 x 8   sc_W2
// frag[((tile*KS+ks)*64+lane)*8+e] = W[k=ks*32+(lane>>4)*8+e][col=tile*16+(lane&15)]
// ---------------------------------------------------------------------------
__global__ __launch_bounds__(256) void wprep(
    const float* __restrict__ sc_W1, const float* __restrict__ attn_W1,
    const float* __restrict__ attn_W2, const float* __restrict__ sc_W2,
    short* __restrict__ frag)
{
    int t = blockIdx.x * 256 + threadIdx.x;
    if (t >= 302080) return;
    float v = 0.f;
    if (t < 199680) {
        int e = t & 7, g = t >> 3;
        int lane = g & 63, h = g >> 6;
        int ks = h % 13, nt = h / 13;
        int k = ks * 32 + (lane >> 4) * 8 + e;
        int cs = (nt % 10) * 16 + (lane & 15);
        if (k < 400 && cs < HID) {
            if (nt < 10)      v = sc_W1[(long)k * HID + cs];
            else if (nt < 20) v = sc_W1[(long)(400 + k) * HID + cs];
            else              v = attn_W1[(long)k * HID + cs];
        }
    } else if (t < 250880) {
        int r = t - 199680;
        int e = r & 7, g = r >> 3;
        int lane = g & 63, h = g >> 6;
        int ks = h % 10, nt = h / 10;
        int k = ks * 32 + (lane >> 4) * 8 + e;
        int cs = nt * 16 + (lane & 15);
        if (k < 300 && cs < HID) v = sc_W1[(long)(800 + k) * HID + cs];
    } else if (t < 276480) {
        int r = t - 250880;
        int e = r & 7, g = r >> 3;
        int lane = g & 63, h = g >> 6;
        int ks = h % 5, nt = h / 5;
        int k = ks * 32 + (lane >> 4) * 8 + e;
        int cs = nt * 16 + (lane & 15);
        if (k < HID && cs < HID) v = attn_W2[(long)k * HID + cs];
    } else {
        int r = t - 276480;
        int e = r & 7, g = r >> 3;
        int lane = g & 63, h = g >> 6;
        int ks = h % 5, nt = h / 5;
        int k = ks * 32 + (lane >> 4) * 8 + e;
        int cs = nt * 16 + (lane & 15);
        if (k < HID && cs < HID) v = sc_W2[(long)k * HID + cs];
    }
    frag[t] = f2bf(v);
}

// ---------------------------------------------------------------------------
// stage 48 (clamped) rows x ks-range [ks0, ks0+KC) of src (row width K) into
// RA in fragment layout: RA[((g*KC+ksl)*64+lane)*8+e]
// ---------------------------------------------------------------------------
template<int KC>
__device__ __forceinline__ void stage48(const float* __restrict__ src, int K,
                                        int ks0, int s0, int tid, short* RA)
{
    for (int idx = tid; idx < 3 * KC * 64; idx += 512) {
        int g = idx / (KC * 64), r = idx - g * (KC * 64);
        int ksl = r >> 6, l2 = r & 63;
        int k = (ks0 + ksl) * 32 + ((l2 >> 4) << 3);
        int row = s0 + g * 16 + (l2 & 15); if (row > T_LEN - 1) row = T_LEN - 1;
        const float* Ar = src + (long)row * K;
        float4 a0 = make_float4(0.f, 0.f, 0.f, 0.f), a1 = a0;
        if (k + 4 <= K) a0 = *(const float4*)&Ar[k];
        if (k + 8 <= K) a1 = *(const float4*)&Ar[k + 4];
        *(bf16x8*)&RA[idx * 8] = cvt8(a0, a1);
    }
}

// ---------------------------------------------------------------------------
// K-chunk MFMA: NT tiles (t0..t0+NT-1) x 3 row-groups, weights double-buffered
// across ksl, A-fragments from RA (LDS).
// ---------------------------------------------------------------------------
template<int KC, int NT>
__device__ __forceinline__ void mm48(const short* __restrict__ fb, const short* RA,
                                     int lane, int ks0, int t0, int kstot,
                                     f32x4 (*acc)[3])
{
    bf16x8 bcur[NT], bnxt[NT];
    #pragma unroll
    for (int t = 0; t < NT; ++t)
        bcur[t] = *(const bf16x8*)&fb[((t0 + t) * kstot + ks0) << 9];
    #pragma unroll
    for (int ksl = 0; ksl < KC; ++ksl) {
        if (ksl < KC - 1) {
            #pragma unroll
            for (int t = 0; t < NT; ++t)
                bnxt[t] = *(const bf16x8*)&fb[((t0 + t) * kstot + ks0 + ksl + 1) << 9];
        }
        bf16x8 af0 = *(const bf16x8*)&RA[((0 * KC + ksl) * 64 + lane) * 8];
        bf16x8 af1 = *(const bf16x8*)&RA[((1 * KC + ksl) * 64 + lane) * 8];
        bf16x8 af2 = *(const bf16x8*)&RA[((2 * KC + ksl) * 64 + lane) * 8];
        #pragma unroll
        for (int t = 0; t < NT; ++t) {
            acc[t][0] = __builtin_amdgcn_mfma_f32_16x16x32_bf16(bcur[t], af0, acc[t][0], 0, 0, 0);
            acc[t][1] = __builtin_amdgcn_mfma_f32_16x16x32_bf16(bcur[t], af1, acc[t][1], 0, 0, 0);
            acc[t][2] = __builtin_amdgcn_mfma_f32_16x16x32_bf16(bcur[t], af2, acc[t][2], 0, 0, 0);
        }
        if (ksl < KC - 1) {
            #pragma unroll
            for (int t = 0; t < NT; ++t) bcur[t] = bnxt[t];
        }
    }
}

// ---------------------------------------------------------------------------
// mega v2: grid 625, 512 threads (8 waves), ~71 KB LDS -> 2 blocks/CU.
// Order: A(2 K-chunks) -> attn2/3 -> logits+softmax -> B(2 K-chunks, embeds
// staged into the same RA buffer) -> span loop (waves 0-3 scorer MFMA, waves
// 4-7 attention-pool phase1, LDS-resident everything).
// Overlays: RA{A-frags -> B-frags -> h1p[2][32*STRU]}, XPs{X1s -> Ps}.
// ---------------------------------------------------------------------------
__global__ __launch_bounds__(512, 4) void mega(
    const float* __restrict__ states, const float* __restrict__ embeds,
    const short* __restrict__ frag,
    const float* __restrict__ scb1, const float* __restrict__ ab1,
    const float* __restrict__ ab2, const float* __restrict__ aW3,
    const float* __restrict__ ab3,
    const float* __restrict__ b2, const float* __restrict__ W3,
    const float* __restrict__ b3,
    float* __restrict__ out)
{
    __shared__ short RA[10752];        // 21,504 B: frag chunks / h1p overlay
    __shared__ short XPs[48 * STRPV]; // 16,896 B: X1s (stride STRU) then Ps (STRPV)
    __shared__ short Us[32 * STRU];   // 10,752 B
    __shared__ short Vs[48 * STRPV];  // 16,896 B
    __shared__ float redl[48][8];
    __shared__ float reds[2][32][2];
    __shared__ float Ls[48], ebuf[48];
    __shared__ float sb1[160], ab1s[160], b2s[160], W3s[160];

    const int tid = threadIdx.x;
    const int w = tid >> 6, lane = tid & 63;
    const int ml = lane & 15, kg = lane >> 4;
    const int s0 = blockIdx.x * 32;          // 625 * 32 = 20000 exact

    for (int t = tid; t < 160; t += 512) {
        sb1[t]  = (t < HID) ? scb1[t] : 0.f;
        ab1s[t] = (t < HID) ? ab1[t]  : 0.f;
        b2s[t]  = (t < HID) ? b2[t]   : 0.f;
        W3s[t]  = (t < HID) ? W3[t]   : 0.f;
    }

    const short* fb = frag + lane * 8;

    // ---------------- Phase A: states @ {U,V,aW1}, 48 rows, K in 2 chunks ----
    const int nTA = (w < 6) ? 4 : 3;
    const int t0A = (w < 6) ? 4 * w : 24 + (w - 6) * 3;
    {
        f32x4 acc[4][3];
        #pragma unroll
        for (int t = 0; t < 4; ++t)
            #pragma unroll
            for (int g = 0; g < 3; ++g)
                acc[t][g] = (f32x4){0.f, 0.f, 0.f, 0.f};

        stage48<7>(states, 400, 0, s0, tid, RA);
        __syncthreads();
        if (w < 6) mm48<7, 4>(fb, RA, lane, 0, t0A, 13, acc);
        else       mm48<7, 3>(fb, RA, lane, 0, t0A, 13, acc);
        __syncthreads();
        stage48<6>(states, 400, 7, s0, tid, RA);
        __syncthreads();
        if (w < 6) mm48<6, 4>(fb, RA, lane, 7, t0A, 13, acc);
        else       mm48<6, 3>(fb, RA, lane, 7, t0A, 13, acc);

        // epilogue: nt<10 -> U (rows 0..31), nt<20 -> V, else X1
        #pragma unroll
        for (int t = 0; t < 4; ++t) {
            if (t < nTA) {
                int nt = t0A + t;
                #pragma unroll
                for (int g = 0; g < 3; ++g) {
                    if (nt < 10) {
                        if (g < 2) {
                            int col0 = nt * 16 + kg * 4;
                            float v[4];
                            #pragma unroll
                            for (int r = 0; r < 4; ++r) {
                                int c = col0 + r;
                                v[r] = (c < HID) ? acc[t][g][r] + sb1[c] : 0.f;
                            }
                            *(uint2*)&Us[(g * 16 + ml) * STRU + col0] =
                                make_uint2(pk2(v[0], v[1]), pk2(v[2], v[3]));
                        }
                    } else if (nt < 20) {
                        int col0 = (nt - 10) * 16 + kg * 4;
                        float v[4];
                        #pragma unroll
                        for (int r = 0; r < 4; ++r) {
                            int c = col0 + r;
                            v[r] = (c < HID) ? acc[t][g][r] : 0.f;
                        }
                        *(uint2*)&Vs[(g * 16 + ml) * STRPV + col0] =
                            make_uint2(pk2(v[0], v[1]), pk2(v[2], v[3]));
                    } else {
                        int col0 = (nt - 20) * 16 + kg * 4;
                        float v[4];
                        #pragma unroll
                        for (int r = 0; r < 4; ++r) {
                            int c = col0 + r;
                            v[r] = (c < HID) ? fmaxf(acc[t][g][r] + ab1s[c], 0.f) : 0.f;
                        }
                        *(uint2*)&XPs[(g * 16 + ml) * STRU + col0] =
                            make_uint2(pk2(v[0], v[1]), pk2(v[2], v[3]));
                    }
                }
            }
        }
    }
    __syncthreads();

    // ---------------- attn layers 2+3 -> redl (X1s consumed here) ----------
    const int nTP = (w < 2) ? 2 : 1;
    const int tB = (w < 2) ? 2 * w : 2 + w;
    {
        const short* fAt2 = frag + 250880 + lane * 8;
        bf16x8 afx[3][5];
        #pragma unroll
        for (int g = 0; g < 3; ++g)
            #pragma unroll
            for (int ks = 0; ks < 5; ++ks)
                afx[g][ks] = *(const bf16x8*)&XPs[(g * 16 + ml) * STRU + ks * 32 + kg * 8];

        float score[3][4];
        #pragma unroll
        for (int g = 0; g < 3; ++g)
            #pragma unroll
            for (int r = 0; r < 4; ++r) score[g][r] = 0.f;

        #pragma unroll
        for (int t = 0; t < 2; ++t) {
            if (t < nTP) {
                int nt = tB + t;
                bf16x8 wb[5];
                #pragma unroll
                for (int ks = 0; ks < 5; ++ks)
                    wb[ks] = *(const bf16x8*)&fAt2[(nt * 5 + ks) << 9];
                f32x4 a2[3];
                a2[0] = (f32x4){0.f, 0.f, 0.f, 0.f};
                a2[1] = (f32x4){0.f, 0.f, 0.f, 0.f};
                a2[2] = (f32x4){0.f, 0.f, 0.f, 0.f};
                #pragma unroll
                for (int g = 0; g < 3; ++g)
                    #pragma unroll
                    for (int ks = 0; ks < 5; ++ks)
                        a2[g] = __builtin_amdgcn_mfma_f32_16x16x32_bf16(afx[g][ks], wb[ks], a2[g], 0, 0, 0);
                int col = nt * 16 + ml;
                float b2v = (col < HID) ? ab2[col] : 0.f;
                float w3v = (col < HID) ? aW3[col] : 0.f;
                #pragma unroll
                for (int g = 0; g < 3; ++g)
                    #pragma unroll
                    for (int r = 0; r < 4; ++r)
                        score[g][r] += fmaxf(a2[g][r] + b2v, 0.f) * w3v;
            }
        }
        #pragma unroll
        for (int g = 0; g < 3; ++g)
            #pragma unroll
            for (int r = 0; r < 4; ++r) {
                score[g][r] += __shfl_xor(score[g][r], 1);
                score[g][r] += __shfl_xor(score[g][r], 2);
                score[g][r] += __shfl_xor(score[g][r], 4);
                score[g][r] += __shfl_xor(score[g][r], 8);
            }
        if (ml == 0) {
            #pragma unroll
            for (int g = 0; g < 3; ++g)
                #pragma unroll
                for (int r = 0; r < 4; ++r)
                    redl[g * 16 + kg * 4 + r][w] = score[g][r];
        }
    }
    __syncthreads();

    // ---------------- logits + chunk softmax (wave 0, wave-synchronous) ----
    if (tid < 48) {
        float Lv = redl[tid][0] + redl[tid][1] + redl[tid][2] + redl[tid][3] +
                   redl[tid][4] + redl[tid][5] + redl[tid][6] + redl[tid][7] + ab3[0];
        Ls[tid] = (tid < 41) ? Lv : -1e30f;
        float M = -1e30f;
        for (int t = 0; t < 41; ++t) M = fmaxf(M, Ls[t]);
        ebuf[tid] = (tid < 41) ? expf(Ls[tid] - M) : 0.f;
    }

    // ---------------- Phase B: embeds @ P-slice, 48 rows, K in 2 chunks ----
    {
        f32x4 accP[2][3];
        #pragma unroll
        for (int t = 0; t < 2; ++t)
            #pragma unroll
            for (int g = 0; g < 3; ++g)
                accP[t][g] = (f32x4){0.f, 0.f, 0.f, 0.f};

        const short* fP = frag + 199680 + lane * 8;
        stage48<5>(embeds, 300, 0, s0, tid, RA);
        __syncthreads();
        if (w < 2) mm48<5, 2>(fP, RA, lane, 0, tB, 10, accP);
        else       mm48<5, 1>(fP, RA, lane, 0, tB, 10, accP);
        __syncthreads();
        stage48<5>(embeds, 300, 5, s0, tid, RA);
        __syncthreads();
        if (w < 2) mm48<5, 2>(fP, RA, lane, 5, tB, 10, accP);
        else       mm48<5, 1>(fP, RA, lane, 5, tB, 10, accP);

        // epilogue: Ps overlays X1s (dead since attn23)
        #pragma unroll
        for (int t = 0; t < 2; ++t) {
            if (t < nTP) {
                int col0 = (tB + t) * 16 + kg * 4;
                #pragma unroll
                for (int g = 0; g < 3; ++g) {
                    float v[4];
                    #pragma unroll
                    for (int r = 0; r < 4; ++r) {
                        int c = col0 + r;
                        v[r] = (c < HID) ? accP[t][g][r] : 0.f;
                    }
                    *(uint2*)&XPs[(g * 16 + ml) * STRPV + col0] =
                        make_uint2(pk2(v[0], v[1]), pk2(v[2], v[3]));
                }
            }
        }
    }

    // ---------------- span loop: waves 4-7 phase1, waves 0-3 phase2 --------
    float Ur[20], accp[20], den = 0.f;
    const int u2 = tid - 256;
    const int iz = u2 >> 3, q = u2 & 7, d0 = 20 * (u2 & 7);
    if (w >= 4) {
        const uint2* U2 = (const uint2*)&Us[iz * STRU + d0];
        #pragma unroll
        for (int c = 0; c < 5; ++c) {
            uint2 uv = U2[c];
            float2 a = ubf2(uv.x), b_ = ubf2(uv.y);
            Ur[4 * c + 0] = a.x;  Ur[4 * c + 1] = a.y;
            Ur[4 * c + 2] = b_.x; Ur[4 * c + 3] = b_.y;
        }
        #pragma unroll
        for (int d = 0; d < 20; ++d) accp[d] = 0.f;
    }
    __syncthreads();   // Ps/Vs/ebuf complete; RA free for h1p overlay

    short* h1p = RA;   // h1p[2][32*STRU]

    auto phase1 = [&](int n, int p) {
        int l = iz + n - 1;                  // local row 0..40
        float e = ebuf[l];
        den += e;
        const uint2* P2 = (const uint2*)&XPs[l * STRPV + d0];
        #pragma unroll
        for (int c = 0; c < 5; ++c) {
            uint2 pv = P2[c];
            float2 a = ubf2(pv.x), b_ = ubf2(pv.y);
            accp[4 * c + 0] += e * a.x;  accp[4 * c + 1] += e * a.y;
            accp[4 * c + 2] += e * b_.x; accp[4 * c + 3] += e * b_.y;
        }
        float invd = 1.f / den;
        const uint2* V2 = (const uint2*)&Vs[l * STRPV + d0];
        #pragma unroll
        for (int c = 0; c < 5; ++c) {
            uint2 vv = V2[c];
            float2 a = ubf2(vv.x), b_ = ubf2(vv.y);
            float x0 = fmaxf(Ur[4 * c + 0] + a.x  + accp[4 * c + 0] * invd, 0.f);
            float x1 = fmaxf(Ur[4 * c + 1] + a.y  + accp[4 * c + 1] * invd, 0.f);
            float x2 = fmaxf(Ur[4 * c + 2] + b_.x + accp[4 * c + 2] * invd, 0.f);
            float x3 = fmaxf(Ur[4 * c + 3] + b_.y + accp[4 * c + 3] * invd, 0.f);
            *(uint2*)&h1p[p * (32 * STRU) + iz * STRU + d0 + 4 * c] =
                make_uint2(pk2(x0, x1), pk2(x2, x3));
        }
    };

    if (w >= 4) phase1(1, 0);
    __syncthreads();

    const int mt = w >> 1;            // phase2 (w<4): m-tile
    const int nt0 = (w & 1) * 5;      // phase2: nt half
    const short* fW2 = frag + 276480;
    const float bb = b3[0];

    for (int n = 1; n <= 10; ++n) {
        const int p = (n - 1) & 1;
        if (w >= 4) {
            if (n < 10) phase1(n + 1, 1 - p);
        } else {
            bf16x8 af[5];
            #pragma unroll
            for (int ks = 0; ks < 5; ++ks)
                af[ks] = *(const bf16x8*)&h1p[p * (32 * STRU) + (mt * 16 + ml) * STRU + ks * 32 + kg * 8];

            float sc[4] = {0.f, 0.f, 0.f, 0.f};
            #pragma unroll
            for (int j = 0; j < 5; ++j) {
                int nt = nt0 + j;
                f32x4 a2 = {0.f, 0.f, 0.f, 0.f};
                #pragma unroll
                for (int ks = 0; ks < 5; ++ks) {
                    bf16x8 bf = *(const bf16x8*)&fW2[(long)(((nt * 5 + ks) << 6) | lane) << 3];
                    a2 = __builtin_amdgcn_mfma_f32_16x16x32_bf16(af[ks], bf, a2, 0, 0, 0);
                }
                int col = nt * 16 + ml;
                float b2v = b2s[col], w3v = W3s[col];
                #pragma unroll
                for (int r = 0; r < 4; ++r)
                    sc[r] += fmaxf(a2[r] + b2v, 0.f) * w3v;
            }
            #pragma unroll
            for (int r = 0; r < 4; ++r) {
                sc[r] += __shfl_xor(sc[r], 1);
                sc[r] += __shfl_xor(sc[r], 2);
                sc[r] += __shfl_xor(sc[r], 4);
                sc[r] += __shfl_xor(sc[r], 8);
            }
            if (ml == 0) {
                #pragma unroll
                for (int r = 0; r < 4; ++r)
                    reds[p][mt * 16 + kg * 4 + r][w & 1] = sc[r];
            }
        }
        __syncthreads();
        if (tid < 32) {
            int S = T_LEN - n + 1;
            int off = (n - 1) * (T_LEN + 1) - (n - 1) * n / 2;
            int sr = s0 + tid;
            if (sr < S) out[off + sr] = reds[p][tid][0] + reds[p][tid][1] + bb;
        }
    }
}

// ---------------------------------------------------------------------------
extern "C" void kernel_launch(void* const* d_in, const int* in_sizes, int n_in,
                              void* d_out, int out_size, void* d_ws, size_t ws_size,
                              hipStream_t stream) {
    const float* embeds  = (const float*)d_in[0];
    const float* states  = (const float*)d_in[1];
    const float* attn_W1 = (const float*)d_in[2];
    const float* attn_b1 = (const float*)d_in[3];
    const float* attn_W2 = (const float*)d_in[4];
    const float* attn_b2 = (const float*)d_in[5];
    const float* attn_W3 = (const float*)d_in[6];
    const float* attn_b3 = (const float*)d_in[7];
    const float* sc_W1   = (const float*)d_in[8];
    const float* sc_b1   = (const float*)d_in[9];
    const float* sc_W2   = (const float*)d_in[10];
    const float* sc_b2   = (const float*)d_in[11];
    const float* sc_W3   = (const float*)d_in[12];
    const float* sc_b3   = (const float*)d_in[13];
    float* out = (float*)d_out;

    short* frag = (short*)d_ws;               // 302,080 shorts

    wprep<<<1180, 256, 0, stream>>>(sc_W1, attn_W1, attn_W2, sc_W2, frag);
    mega<<<625, 512, 0, stream>>>(states, embeds, frag, sc_b1, attn_b1,
                                  attn_b2, attn_W3, attn_b3,
                                  sc_b2, sc_W3, sc_b3, out);
}

// Round 5
// 190.747 us; speedup vs baseline: 1.2804x; 1.2804x over previous
//
#include <hip/hip_runtime.h>
#include <hip/hip_bf16.h>
#include <math.h>

#define T_LEN 20000
#define HID 150

typedef __attribute__((ext_vector_type(8))) __bf16 bf16x8;
typedef __attribute__((ext_vector_type(4))) float f32x4;

__device__ __forceinline__ short f2bf(float f) {
    unsigned u = __float_as_uint(f);
    u = (u + 0x7fff + ((u >> 16) & 1)) >> 16;
    return (short)u;
}

__device__ __forceinline__ unsigned pk2(float a, float b) {
    __hip_bfloat162 h = __float22bfloat162_rn(make_float2(a, b));
    return *(unsigned*)&h;
}

__device__ __forceinline__ bf16x8 cvt8(float4 a, float4 b) {
    union { unsigned u[4]; bf16x8 v; } r;
    r.u[0] = pk2(a.x, a.y);
    r.u[1] = pk2(a.z, a.w);
    r.u[2] = pk2(b.x, b.y);
    r.u[3] = pk2(b.z, b.w);
    return r.v;
}

__device__ __forceinline__ float2 ubf2(unsigned u) {
    return make_float2(__uint_as_float(u << 16),
                       __uint_as_float(u & 0xffff0000u));
}

// ---------------------------------------------------------------------------
// Fragment-order weight regions (shorts), lane = consuming lane (ml|kg<<4):
//   fragA  [0,199680)        30 tiles x 13 ks x 64 x 8   U(0-9) V(10-19) aW1(20-29)
//   fragP  [199680,250880)   10 tiles x 10 ks x 64 x 8   sc_W1 rows 800..1099
//   fragAt2[250880,276480)   10 tiles x  5 ks x 64 x 8   attn_W2
//   fragW2 [276480,302080)   10 tiles x  5 ks x 64 x 8   sc_W2
// frag[((tile*KS+ks)*64+lane)*8+e] = W[k=ks*32+(lane>>4)*8+e][col=tile*16+(lane&15)]
// ---------------------------------------------------------------------------
__global__ __launch_bounds__(256) void wprep(
    const float* __restrict__ sc_W1, const float* __restrict__ attn_W1,
    const float* __restrict__ attn_W2, const float* __restrict__ sc_W2,
    short* __restrict__ frag)
{
    int t = blockIdx.x * 256 + threadIdx.x;
    if (t >= 302080) return;
    float v = 0.f;
    if (t < 199680) {
        int e = t & 7, g = t >> 3;
        int lane = g & 63, h = g >> 6;
        int ks = h % 13, nt = h / 13;
        int k = ks * 32 + (lane >> 4) * 8 + e;
        int cs = (nt % 10) * 16 + (lane & 15);
        if (k < 400 && cs < HID) {
            if (nt < 10)      v = sc_W1[(long)k * HID + cs];
            else if (nt < 20) v = sc_W1[(long)(400 + k) * HID + cs];
            else              v = attn_W1[(long)k * HID + cs];
        }
    } else if (t < 250880) {
        int r = t - 199680;
        int e = r & 7, g = r >> 3;
        int lane = g & 63, h = g >> 6;
        int ks = h % 10, nt = h / 10;
        int k = ks * 32 + (lane >> 4) * 8 + e;
        int cs = nt * 16 + (lane & 15);
        if (k < 300 && cs < HID) v = sc_W1[(long)(800 + k) * HID + cs];
    } else if (t < 276480) {
        int r = t - 250880;
        int e = r & 7, g = r >> 3;
        int lane = g & 63, h = g >> 6;
        int ks = h % 5, nt = h / 5;
        int k = ks * 32 + (lane >> 4) * 8 + e;
        int cs = nt * 16 + (lane & 15);
        if (k < HID && cs < HID) v = attn_W2[(long)k * HID + cs];
    } else {
        int r = t - 276480;
        int e = r & 7, g = r >> 3;
        int lane = g & 63, h = g >> 6;
        int ks = h % 5, nt = h / 5;
        int k = ks * 32 + (lane >> 4) * 8 + e;
        int cs = nt * 16 + (lane & 15);
        if (k < HID && cs < HID) v = sc_W2[(long)k * HID + cs];
    }
    frag[t] = f2bf(v);
}

// ---------------------------------------------------------------------------
// fusedAP v5: 32 rows/block, grid 625, 384 threads (6 waves). v3 shape +
// sched_barrier(0)-PINNED depth-2 software pipeline on the weight loads:
// per ks, the 5 loads for ks+2 are issued in a group the scheduler cannot
// sink (SB(0) fence), so 10 loads stay in flight under the 10 MFMAs.
// Static wbuf[3][5] indices (full unroll) keep everything in registers.
// ---------------------------------------------------------------------------
__global__ __launch_bounds__(384, 3) void fusedAP(
    const float* __restrict__ states, const float* __restrict__ embeds,
    const short* __restrict__ frag,
    const float* __restrict__ scb1, const float* __restrict__ ab1,
    const float* __restrict__ ab2, const float* __restrict__ aW3,
    const float* __restrict__ ab3,
    short* __restrict__ Ubf, short* __restrict__ Vbf, short* __restrict__ Pbf,
    float* __restrict__ logits)
{
    __shared__ short As[2 * 13 * 64 * 8];   // 26,624 B (reused for embeds)
    __shared__ short h1s[32 * 168];         // 10,752 B
    __shared__ float red[32][6];
    __shared__ float sb1[160], ab1s[160];
    const int tid = threadIdx.x;
    const int w = tid >> 6, lane = tid & 63;
    const int ml = lane & 15, kg = lane >> 4;
    const int m0 = blockIdx.x * 32;          // 625 * 32 = 20000 exact

    for (int t = tid; t < 160; t += 384) {
        sb1[t]  = (t < HID) ? scb1[t] : 0.f;
        ab1s[t] = (t < HID) ? ab1[t]  : 0.f;
    }
    // ---- stage states (32 rows x K=400) into As, fragment layout ----
    for (int idx = tid; idx < 2 * 13 * 64; idx += 384) {
        int g = idx / 832, r = idx - g * 832;
        int ks = r >> 6, l2 = r & 63;
        int k = ks * 32 + ((l2 >> 4) << 3);
        const float* Ar = states + (long)(m0 + g * 16 + (l2 & 15)) * 400;
        float4 a0 = make_float4(0.f, 0.f, 0.f, 0.f), a1 = a0;
        if (k + 4 <= 400) a0 = *(const float4*)&Ar[k];
        if (k + 8 <= 400) a1 = *(const float4*)&Ar[k + 4];
        *(bf16x8*)&As[idx * 8] = cvt8(a0, a1);
    }
    __syncthreads();

    // ---------------- Phase A: states @ {U,V,aW1} ----------------
    f32x4 acc[5][2];
    #pragma unroll
    for (int t = 0; t < 5; ++t)
        #pragma unroll
        for (int g = 0; g < 2; ++g)
            acc[t][g] = (f32x4){0.f, 0.f, 0.f, 0.f};

    const short* fb = frag + lane * 8;
    const int t5 = w * 5;

    {
        bf16x8 wbuf[3][5];
        #pragma unroll
        for (int t = 0; t < 5; ++t)
            wbuf[0][t] = *(const bf16x8*)&fb[((t5 + t) * 13 + 0) << 9];
        #pragma unroll
        for (int t = 0; t < 5; ++t)
            wbuf[1][t] = *(const bf16x8*)&fb[((t5 + t) * 13 + 1) << 9];
        __builtin_amdgcn_sched_barrier(0);

        #pragma unroll
        for (int ks = 0; ks < 13; ++ks) {
            if (ks + 2 < 13) {
                #pragma unroll
                for (int t = 0; t < 5; ++t)
                    wbuf[(ks + 2) % 3][t] = *(const bf16x8*)&fb[((t5 + t) * 13 + ks + 2) << 9];
            }
            __builtin_amdgcn_sched_barrier(0);
            bf16x8 af0 = *(const bf16x8*)&As[(ks * 64 + lane) * 8];
            bf16x8 af1 = *(const bf16x8*)&As[(832 + ks * 64 + lane) * 8];
            #pragma unroll
            for (int t = 0; t < 5; ++t) {
                acc[t][0] = __builtin_amdgcn_mfma_f32_16x16x32_bf16(wbuf[ks % 3][t], af0, acc[t][0], 0, 0, 0);
                acc[t][1] = __builtin_amdgcn_mfma_f32_16x16x32_bf16(wbuf[ks % 3][t], af1, acc[t][1], 0, 0, 0);
            }
        }
    }

    // epilogue A (wave-uniform output type)
    #pragma unroll
    for (int t = 0; t < 5; ++t) {
        int nt = t5 + t;
        #pragma unroll
        for (int g = 0; g < 2; ++g) {
            if (w < 2) {                      // U (+sc_b1)
                int col0 = nt * 16 + kg * 4;
                float v[4];
                #pragma unroll
                for (int r = 0; r < 4; ++r) {
                    int c = col0 + r;
                    v[r] = (c < HID) ? acc[t][g][r] + sb1[c] : 0.f;
                }
                *(uint2*)&Ubf[(long)(m0 + g * 16 + ml) * 160 + col0] =
                    make_uint2(pk2(v[0], v[1]), pk2(v[2], v[3]));
            } else if (w < 4) {               // V
                int col0 = (nt - 10) * 16 + kg * 4;
                float v[4];
                #pragma unroll
                for (int r = 0; r < 4; ++r) {
                    int c = col0 + r;
                    v[r] = (c < HID) ? acc[t][g][r] : 0.f;
                }
                *(uint2*)&Vbf[(long)(m0 + g * 16 + ml) * 160 + col0] =
                    make_uint2(pk2(v[0], v[1]), pk2(v[2], v[3]));
            } else {                          // X1 -> relu -> bf16 LDS
                int col0 = (nt - 20) * 16 + kg * 4;
                float v[4];
                #pragma unroll
                for (int r = 0; r < 4; ++r) {
                    int c = col0 + r;
                    v[r] = (c < HID) ? fmaxf(acc[t][g][r] + ab1s[c], 0.f) : 0.f;
                }
                *(uint2*)&h1s[(g * 16 + ml) * 168 + col0] =
                    make_uint2(pk2(v[0], v[1]), pk2(v[2], v[3]));
            }
        }
    }
    __syncthreads();   // As reads done + h1s complete

    // ---- restage embeds (32 rows x K=300) into As ----
    for (int idx = tid; idx < 2 * 10 * 64; idx += 384) {
        int g = idx / 640, r = idx - g * 640;
        int ks = r >> 6, l2 = r & 63;
        int k = ks * 32 + ((l2 >> 4) << 3);
        const float* Er = embeds + (long)(m0 + g * 16 + (l2 & 15)) * 300;
        float4 a0 = make_float4(0.f, 0.f, 0.f, 0.f), a1 = a0;
        if (k + 4 <= 300) a0 = *(const float4*)&Er[k];
        if (k + 8 <= 300) a1 = *(const float4*)&Er[k + 4];
        *(bf16x8*)&As[idx * 8] = cvt8(a0, a1);
    }
    __syncthreads();

    // ---------------- Phase B: embeds @ P-slice ----------------
    const int tB = (w < 4) ? 2 * w : (w == 4 ? 8 : 9);
    const int nTP = (w < 4) ? 2 : 1;
    {
        f32x4 accP[2][2];
        #pragma unroll
        for (int t = 0; t < 2; ++t)
            #pragma unroll
            for (int g = 0; g < 2; ++g)
                accP[t][g] = (f32x4){0.f, 0.f, 0.f, 0.f};

        const short* fP = frag + 199680 + lane * 8;
        bf16x8 pbuf[3][2];
        #pragma unroll
        for (int t = 0; t < 2; ++t)
            if (t < nTP) {
                pbuf[0][t] = *(const bf16x8*)&fP[((tB + t) * 10 + 0) << 9];
                pbuf[1][t] = *(const bf16x8*)&fP[((tB + t) * 10 + 1) << 9];
            }
        __builtin_amdgcn_sched_barrier(0);

        #pragma unroll
        for (int ks = 0; ks < 10; ++ks) {
            if (ks + 2 < 10) {
                #pragma unroll
                for (int t = 0; t < 2; ++t)
                    if (t < nTP)
                        pbuf[(ks + 2) % 3][t] = *(const bf16x8*)&fP[((tB + t) * 10 + ks + 2) << 9];
            }
            __builtin_amdgcn_sched_barrier(0);
            bf16x8 af0 = *(const bf16x8*)&As[(ks * 64 + lane) * 8];
            bf16x8 af1 = *(const bf16x8*)&As[(640 + ks * 64 + lane) * 8];
            #pragma unroll
            for (int t = 0; t < 2; ++t) {
                if (t < nTP) {
                    accP[t][0] = __builtin_amdgcn_mfma_f32_16x16x32_bf16(pbuf[ks % 3][t], af0, accP[t][0], 0, 0, 0);
                    accP[t][1] = __builtin_amdgcn_mfma_f32_16x16x32_bf16(pbuf[ks % 3][t], af1, accP[t][1], 0, 0, 0);
                }
            }
        }

        #pragma unroll
        for (int t = 0; t < 2; ++t) {
            if (t < nTP) {
                int col0 = (tB + t) * 16 + kg * 4;
                #pragma unroll
                for (int g = 0; g < 2; ++g) {
                    float v[4];
                    #pragma unroll
                    for (int r = 0; r < 4; ++r) {
                        int c = col0 + r;
                        v[r] = (c < HID) ? accP[t][g][r] : 0.f;
                    }
                    *(uint2*)&Pbf[(long)(m0 + g * 16 + ml) * 160 + col0] =
                        make_uint2(pk2(v[0], v[1]), pk2(v[2], v[3]));
                }
            }
        }
    }

    // ---------------- Phase C: attn layers 2+3 ----------------
    const short* fAt2 = frag + 250880 + lane * 8;
    bf16x8 af2[2][5];
    #pragma unroll
    for (int g = 0; g < 2; ++g)
        #pragma unroll
        for (int ks = 0; ks < 5; ++ks)
            af2[g][ks] = *(const bf16x8*)&h1s[(g * 16 + ml) * 168 + ks * 32 + kg * 8];

    float score[2][4];
    #pragma unroll
    for (int g = 0; g < 2; ++g)
        #pragma unroll
        for (int r = 0; r < 4; ++r) score[g][r] = 0.f;

    #pragma unroll
    for (int t = 0; t < 2; ++t) {
        if (t < nTP) {
            int nt = tB + t;
            bf16x8 wb[5];
            #pragma unroll
            for (int ks = 0; ks < 5; ++ks)
                wb[ks] = *(const bf16x8*)&fAt2[(nt * 5 + ks) << 9];
            f32x4 a2[2];
            a2[0] = (f32x4){0.f, 0.f, 0.f, 0.f};
            a2[1] = (f32x4){0.f, 0.f, 0.f, 0.f};
            #pragma unroll
            for (int g = 0; g < 2; ++g)
                #pragma unroll
                for (int ks = 0; ks < 5; ++ks)
                    a2[g] = __builtin_amdgcn_mfma_f32_16x16x32_bf16(af2[g][ks], wb[ks], a2[g], 0, 0, 0);
            int col = nt * 16 + ml;
            float b2v = (col < HID) ? ab2[col] : 0.f;
            float w3v = (col < HID) ? aW3[col] : 0.f;
            #pragma unroll
            for (int g = 0; g < 2; ++g)
                #pragma unroll
                for (int r = 0; r < 4; ++r)
                    score[g][r] += fmaxf(a2[g][r] + b2v, 0.f) * w3v;
        }
    }
    #pragma unroll
    for (int g = 0; g < 2; ++g)
        #pragma unroll
        for (int r = 0; r < 4; ++r) {
            score[g][r] += __shfl_xor(score[g][r], 1);
            score[g][r] += __shfl_xor(score[g][r], 2);
            score[g][r] += __shfl_xor(score[g][r], 4);
            score[g][r] += __shfl_xor(score[g][r], 8);
        }
    if (ml == 0) {
        #pragma unroll
        for (int g = 0; g < 2; ++g)
            #pragma unroll
            for (int r = 0; r < 4; ++r)
                red[g * 16 + kg * 4 + r][w] = score[g][r];
    }
    __syncthreads();
    if (tid < 32)
        logits[m0 + tid] = red[tid][0] + red[tid][1] + red[tid][2] +
                           red[tid][3] + red[tid][4] + red[tid][5] + ab3[0];
}

// ---------------------------------------------------------------------------
// span_all: grid (625, 2). Block (x,y): 32 spans of chunk x, widths n in
// {1..5} (y=0) or {6..10} (y=1, 5-row L2-hit prefix). SOFTWARE-PIPELINED:
// double-buffered h1s/red, phase1(n+1) overlaps phase2(n), ONE sync per n.
// v5: af hoisted above phase1 (r1); fW2 j-loop ping-pong in wj[2][5] with a
// sched_barrier(0)-pinned load group (same discipline as fusedAP).
// ---------------------------------------------------------------------------
__global__ __launch_bounds__(256) void span_all(
    const short* __restrict__ Ubf, const short* __restrict__ Vbf,
    const short* __restrict__ Pbf, const float* __restrict__ logits,
    const short* __restrict__ fW2, const float* __restrict__ b2,
    const float* __restrict__ W3, const float* __restrict__ b3,
    float* __restrict__ out)
{
    __shared__ short h1s[2][32 * 168];
    __shared__ float red[2][32][2];
    __shared__ float Ls[48], ebuf[48];
    __shared__ float b2s[160], W3s[160];

    const int tid = threadIdx.x;
    const int s0 = blockIdx.x * 32;
    const int nlo = blockIdx.y ? 6 : 1;
    const int nhi = blockIdx.y ? 10 : 5;

    if (tid < 48) {
        int r = s0 + tid; if (r > T_LEN - 1) r = T_LEN - 1;
        Ls[tid] = (tid < 41) ? logits[r] : -1e30f;
    }
    for (int t = tid; t < 160; t += 256) {
        b2s[t] = (t < HID) ? b2[t] : 0.f;
        W3s[t] = (t < HID) ? W3[t] : 0.f;
    }
    __syncthreads();
    if (tid < 48) {
        float M = -1e30f;
        for (int t = 0; t < 41; ++t) M = fmaxf(M, Ls[t]);
        ebuf[tid] = (tid < 41) ? expf(Ls[tid] - M) : 0.f;
    }
    __syncthreads();

    const int i = tid >> 3;       // span 0..31
    const int q = tid & 7;        // dim block [20q, 20q+20)
    const int d0 = 20 * q;
    const int s = s0 + i;
    int su = s; if (su > T_LEN - 1) su = T_LEN - 1;

    float Ur[20];
    {
        const uint2* U2 = (const uint2*)&Ubf[(long)su * 160 + d0];
        #pragma unroll
        for (int c = 0; c < 5; ++c) {
            uint2 uv = U2[c];
            float2 a = ubf2(uv.x), b_ = ubf2(uv.y);
            Ur[4 * c + 0] = a.x;  Ur[4 * c + 1] = a.y;
            Ur[4 * c + 2] = b_.x; Ur[4 * c + 3] = b_.y;
        }
    }
    float accp[20];
    #pragma unroll
    for (int d = 0; d < 20; ++d) accp[d] = 0.f;
    float den = 0.f;

    // prefix j = 0..nlo-2 (only y=1: 5 rows, L2-hit)
    for (int j = 0; j < nlo - 1; ++j) {
        int rr_ = s + j; if (rr_ > T_LEN - 1) rr_ = T_LEN - 1;
        float e = ebuf[i + j];
        den += e;
        const uint2* P2 = (const uint2*)&Pbf[(long)rr_ * 160 + d0];
        #pragma unroll
        for (int c = 0; c < 5; ++c) {
            uint2 pv = P2[c];
            float2 a = ubf2(pv.x), b_ = ubf2(pv.y);
            accp[4 * c + 0] += e * a.x;  accp[4 * c + 1] += e * a.y;
            accp[4 * c + 2] += e * b_.x; accp[4 * c + 3] += e * b_.y;
        }
    }

    const int w = tid >> 6, lane = tid & 63;
    const int ml = lane & 15, kg = lane >> 4;
    const int mt = w >> 1;            // m-tile (spans mt*16..+15)
    const int nt0 = (w & 1) * 5;      // nt half
    const float bb = b3[0];
    const short* fw = fW2 + ((nt0 * 5) << 9) + lane * 8;

    // phase1 for n: update accp/den, write h1 -> h1s[p]
    auto phase1 = [&](int n, int p) {
        int rr_ = s + n - 1; if (rr_ > T_LEN - 1) rr_ = T_LEN - 1;
        float e = ebuf[i + n - 1];
        den += e;
        {
            const uint2* P2 = (const uint2*)&Pbf[(long)rr_ * 160 + d0];
            #pragma unroll
            for (int c = 0; c < 5; ++c) {
                uint2 pv = P2[c];
                float2 a = ubf2(pv.x), b_ = ubf2(pv.y);
                accp[4 * c + 0] += e * a.x;  accp[4 * c + 1] += e * a.y;
                accp[4 * c + 2] += e * b_.x; accp[4 * c + 3] += e * b_.y;
            }
        }
        float invd = 1.f / den;
        {
            const uint2* V2 = (const uint2*)&Vbf[(long)rr_ * 160 + d0];
            #pragma unroll
            for (int c = 0; c < 5; ++c) {
                uint2 vv = V2[c];
                float2 a = ubf2(vv.x), b_ = ubf2(vv.y);
                float x0 = fmaxf(Ur[4 * c + 0] + a.x  + accp[4 * c + 0] * invd, 0.f);
                float x1 = fmaxf(Ur[4 * c + 1] + a.y  + accp[4 * c + 1] * invd, 0.f);
                float x2 = fmaxf(Ur[4 * c + 2] + b_.x + accp[4 * c + 2] * invd, 0.f);
                float x3 = fmaxf(Ur[4 * c + 3] + b_.y + accp[4 * c + 3] * invd, 0.f);
                *(uint2*)&h1s[p][i * 168 + d0 + 4 * c] =
                    make_uint2(pk2(x0, x1), pk2(x2, x3));
            }
        }
    };

    phase1(nlo, 0);
    __syncthreads();

    for (int n = nlo; n <= nhi; ++n) {
        const int p = (n - nlo) & 1;

        // phase-2 LDS operands for n: issue before the overlapped phase1
        bf16x8 af[5];
        #pragma unroll
        for (int ks = 0; ks < 5; ++ks)
            af[ks] = *(const bf16x8*)&h1s[p][(mt * 16 + ml) * 168 + ks * 32 + kg * 8];

        // phase 1 for n+1 into the other buffer (overlaps loads + MFMAs)
        if (n < nhi) phase1(n + 1, 1 - p);

        // phase 2 on h1s[p]: j-loop, ping-pong wj + pinned load groups
        bf16x8 wj[2][5];
        #pragma unroll
        for (int ks = 0; ks < 5; ++ks)
            wj[0][ks] = *(const bf16x8*)&fw[ks << 9];

        float sc[4] = {0.f, 0.f, 0.f, 0.f};
        #pragma unroll
        for (int j = 0; j < 5; ++j) {
            if (j < 4) {
                #pragma unroll
                for (int ks = 0; ks < 5; ++ks)
                    wj[(j + 1) & 1][ks] = *(const bf16x8*)&fw[((j + 1) * 5 + ks) << 9];
            }
            __builtin_amdgcn_sched_barrier(0);
            f32x4 a2 = {0.f, 0.f, 0.f, 0.f};
            #pragma unroll
            for (int ks = 0; ks < 5; ++ks)
                a2 = __builtin_amdgcn_mfma_f32_16x16x32_bf16(af[ks], wj[j & 1][ks], a2, 0, 0, 0);
            int col = (nt0 + j) * 16 + ml;
            float b2v = b2s[col], w3v = W3s[col];
            #pragma unroll
            for (int r = 0; r < 4; ++r)
                sc[r] += fmaxf(a2[r] + b2v, 0.f) * w3v;
        }
        #pragma unroll
        for (int r = 0; r < 4; ++r) {
            sc[r] += __shfl_xor(sc[r], 1);
            sc[r] += __shfl_xor(sc[r], 2);
            sc[r] += __shfl_xor(sc[r], 4);
            sc[r] += __shfl_xor(sc[r], 8);
        }
        if (ml == 0) {
            #pragma unroll
            for (int r = 0; r < 4; ++r)
                red[p][mt * 16 + kg * 4 + r][w & 1] = sc[r];
        }
        __syncthreads();
        if (tid < 32) {
            int S = T_LEN - n + 1;
            int off = (n - 1) * (T_LEN + 1) - (n - 1) * n / 2;
            int sr = s0 + tid;
            if (sr < S) out[off + sr] = red[p][tid][0] + red[p][tid][1] + bb;
        }
    }
}

// ---------------------------------------------------------------------------
extern "C" void kernel_launch(void* const* d_in, const int* in_sizes, int n_in,
                              void* d_out, int out_size, void* d_ws, size_t ws_size,
                              hipStream_t stream) {
    const float* embeds  = (const float*)d_in[0];
    const float* states  = (const float*)d_in[1];
    const float* attn_W1 = (const float*)d_in[2];
    const float* attn_b1 = (const float*)d_in[3];
    const float* attn_W2 = (const float*)d_in[4];
    const float* attn_b2 = (const float*)d_in[5];
    const float* attn_W3 = (const float*)d_in[6];
    const float* attn_b3 = (const float*)d_in[7];
    const float* sc_W1   = (const float*)d_in[8];
    const float* sc_b1   = (const float*)d_in[9];
    const float* sc_W2   = (const float*)d_in[10];
    const float* sc_b2   = (const float*)d_in[11];
    const float* sc_W3   = (const float*)d_in[12];
    const float* sc_b3   = (const float*)d_in[13];
    float* out = (float*)d_out;

    short* wsS = (short*)d_ws;
    short* Ubf = wsS;                         // [20000][160] bf16
    short* Vbf = wsS + 3200256;
    short* Pbf = wsS + 6400512;
    short* frag = wsS + 9600768;              // 302,080 shorts
    float* logits = (float*)(wsS + 9902848);  // 20,000 floats

    wprep<<<1180, 256, 0, stream>>>(sc_W1, attn_W1, attn_W2, sc_W2, frag);
    fusedAP<<<625, 384, 0, stream>>>(states, embeds, frag, sc_b1, attn_b1,
                                     attn_b2, attn_W3, attn_b3,
                                     Ubf, Vbf, Pbf, logits);
    span_all<<<dim3(625, 2), 256, 0, stream>>>(Ubf, Vbf, Pbf, logits,
                                               frag + 276480, sc_b2, sc_W3, sc_b3,
                                               out);
}